// Round 4
// baseline (992.768 us; speedup 1.0000x reference)
//
#include <hip/hip_runtime.h>
#include <hip/hip_bf16.h>

#define NN 50000
#define NE 600000
#define NG 64
#define PD 128
#define HD 256
#define NPAD 50048   // ceil(NN/64)*64
#define NPART 49     // ceil(NN/1024)

typedef __bf16 bf16;
typedef __bf16 bf16x8 __attribute__((ext_vector_type(8)));
typedef float f32x4 __attribute__((ext_vector_type(4)));

__device__ __forceinline__ float lrelu(float x) { return x > 0.f ? x : 0.01f * x; }

// ---------------- weights -> bf16 ----------------
__global__ void k_convert_weights(const float* __restrict__ pw, const float* __restrict__ w1,
                                  const float* __restrict__ w2, bf16* __restrict__ pw16,
                                  bf16* __restrict__ w116, bf16* __restrict__ w216) {
    int i = blockIdx.x * 256 + threadIdx.x;
    if (i < PD * PD) pw16[i] = (bf16)pw[i];
    if (i < HD * PD) w116[i] = (bf16)w1[i];
    if (i < PD * HD) w216[i] = (bf16)w2[i];
}

// ---------------- GraphNorm stats (batch is sorted) ----------------
__global__ __launch_bounds__(128) void k_gn_stats(const float* __restrict__ x,
                                                  const int* __restrict__ batch,
                                                  float* __restrict__ gsum, float* __restrict__ gsq,
                                                  int* __restrict__ gcnt) {
    int p = threadIdx.x;  // 128
    int base = blockIdx.x * 64;
    int end = min(base + 64, NN);
    float s = 0.f, q = 0.f;
    int cur = batch[base];
    int runstart = base;
    for (int i = base; i < end; ++i) {
        int g = batch[i];
        if (g != cur) {
            atomicAdd(&gsum[cur * PD + p], s);
            atomicAdd(&gsq[cur * PD + p], q);
            if (p == 0) atomicAdd(&gcnt[cur], i - runstart);
            s = 0.f; q = 0.f; cur = g; runstart = i;
        }
        float v = x[(size_t)i * PD + p];
        s += v; q += v * v;
    }
    atomicAdd(&gsum[cur * PD + p], s);
    atomicAdd(&gsq[cur * PD + p], q);
    if (p == 0) atomicAdd(&gcnt[cur], end - runstart);
}

__global__ void k_gn_finalize(const float* __restrict__ gsum, const float* __restrict__ gsq,
                              const int* __restrict__ gcnt, const float* __restrict__ gw,
                              const float* __restrict__ gb, const float* __restrict__ gms,
                              float* __restrict__ gA, float* __restrict__ gB) {
    int i = blockIdx.x * 256 + threadIdx.x;
    if (i >= NG * PD) return;
    int p = i & (PD - 1);
    float c = (float)max(gcnt[i >> 7], 1);
    float m = gsum[i] / c;
    float q = gsq[i] / c;
    float s = gms[p];
    float var = q - m * m * (2.f * s - s * s);
    float inv = rsqrtf(var + 1e-5f);
    float a = gw[p] * inv;
    gA[i] = a;
    gB[i] = gb[p] - a * s * m;
}

__global__ void k_compute_h(const float* __restrict__ x, const int* __restrict__ batch,
                            const float* __restrict__ gA, const float* __restrict__ gB,
                            bf16* __restrict__ h) {
    size_t i = (size_t)blockIdx.x * 256 + threadIdx.x;
    if (i >= (size_t)NN * PD) return;
    int node = (int)(i >> 7), p = (int)(i & (PD - 1));
    int g = batch[node];
    float v = gA[g * PD + p] * x[i] + gB[g * PD + p];
    h[i] = (bf16)lrelu(v);
}

// ---------------- edge BN stats (float4 loads, 8 rows in flight) ----------------
__global__ __launch_bounds__(256) void k_bn_stats(const float* __restrict__ ea,
                                                  float* __restrict__ colsum,
                                                  float* __restrict__ colsq) {
    const int t = threadIdx.x;
    const int cq = (t & 31) * 4;   // column quad
    const int ro = t >> 5;         // row offset 0..7
    const size_t base = (size_t)blockIdx.x * 512;
    f32x4 s = {0.f, 0.f, 0.f, 0.f}, q = {0.f, 0.f, 0.f, 0.f};
    for (int r = 0; r < 64; ++r) {
        size_t e = base + (size_t)r * 8 + ro;
        if (e < NE) {
            float4 v = *(const float4*)(ea + e * PD + cq);
            s[0] += v.x; s[1] += v.y; s[2] += v.z; s[3] += v.w;
            q[0] += v.x * v.x; q[1] += v.y * v.y; q[2] += v.z * v.z; q[3] += v.w * v.w;
        }
    }
    __shared__ f32x4 shA[256], shB[256];
    shA[t] = s; shB[t] = q;
    __syncthreads();
    if (t < 128) { shA[t] += shA[t + 128]; shB[t] += shB[t + 128]; }
    __syncthreads();
    if (t < 64) { shA[t] += shA[t + 64]; shB[t] += shB[t + 64]; }
    __syncthreads();
    if (t < 32) {
        f32x4 a = shA[t] + shA[t + 32];
        f32x4 b = shB[t] + shB[t + 32];
#pragma unroll
        for (int i = 0; i < 4; ++i) {
            atomicAdd(&colsum[t * 4 + i], a[i]);
            atomicAdd(&colsq[t * 4 + i], b[i]);
        }
    }
}

__global__ void k_bn_finalize(const float* __restrict__ colsum, const float* __restrict__ colsq,
                              const float* __restrict__ gamma, const float* __restrict__ beta,
                              float* __restrict__ escale, float* __restrict__ eshift) {
    int p = threadIdx.x;
    float m = colsum[p] / (float)NE;
    float v = colsq[p] / (float)NE - m * m;
    float sc = gamma[p] * rsqrtf(v + 1e-5f);
    escale[p] = sc;
    eshift[p] = beta[p] - sc * m;
}

// ---------------- CSR by dst ----------------
__global__ void k_deg(const int* __restrict__ dst, int* __restrict__ deg) {
    int e = blockIdx.x * 256 + threadIdx.x;
    if (e < NE) atomicAdd(&deg[dst[e]], 1);
}

__global__ __launch_bounds__(256) void k_scan_part(const int* __restrict__ deg,
                                                   int* __restrict__ part) {
    __shared__ int sh[256];
    int b = blockIdx.x, t = threadIdx.x;
    int base = b * 1024;
    int s = 0;
#pragma unroll
    for (int k = 0; k < 4; ++k) {
        int i = base + k * 256 + t;
        if (i < NN) s += deg[i];
    }
    sh[t] = s;
    __syncthreads();
    for (int st = 128; st > 0; st >>= 1) {
        if (t < st) sh[t] += sh[t + st];
        __syncthreads();
    }
    if (t == 0) part[b] = sh[0];
}

__global__ void k_scan_tops(const int* __restrict__ part, int* __restrict__ ptot) {
    int t = threadIdx.x;  // 64
    int v = (t < NPART) ? part[t] : 0;
    int orig = v;
    for (int s = 1; s < 64; s <<= 1) {
        int u = __shfl_up(v, s);
        if (t >= s) v += u;
    }
    if (t < NPART) ptot[t] = v - orig;  // exclusive
}

__global__ __launch_bounds__(256) void k_scan_final(const int* __restrict__ deg,
                                                    const int* __restrict__ ptot,
                                                    int* __restrict__ offs) {
    __shared__ int sh[256];
    int b = blockIdx.x, t = threadIdx.x;
    int i0 = b * 1024 + t * 4;
    int v0 = (i0 + 0 < NN) ? deg[i0 + 0] : 0;
    int v1 = (i0 + 1 < NN) ? deg[i0 + 1] : 0;
    int v2 = (i0 + 2 < NN) ? deg[i0 + 2] : 0;
    int v3 = (i0 + 3 < NN) ? deg[i0 + 3] : 0;
    int s = v0 + v1 + v2 + v3;
    sh[t] = s;
    __syncthreads();
    for (int st = 1; st < 256; st <<= 1) {
        int add = (t >= st) ? sh[t - st] : 0;
        __syncthreads();
        sh[t] += add;
        __syncthreads();
    }
    int pre = sh[t] - s + ptot[b];
    if (i0 + 0 < NN) offs[i0 + 0] = pre;
    if (i0 + 1 < NN) offs[i0 + 1] = pre + v0;
    if (i0 + 2 < NN) offs[i0 + 2] = pre + v0 + v1;
    if (i0 + 3 < NN) offs[i0 + 3] = pre + v0 + v1 + v2;
}

__global__ void k_scatter(const int* __restrict__ dst, const int* __restrict__ offs,
                          int* __restrict__ cursor, int* __restrict__ perm) {
    int e = blockIdx.x * 256 + threadIdx.x;
    if (e < NE) {
        int d = dst[e];
        int pos = atomicAdd(&cursor[d], 1);
        perm[offs[d] + pos] = e;
    }
}

// ---------------- edge norm + GEMM: attr = leaky(bn(ea)) @ W^T + b ----------------
// Direct-global A-fragments; single barrier; bf16 LDS transpose (17.4 KB -> 8 blocks/CU).
// out1 = (f32)bf16(attr) + ea ; attr16 = bf16(attr) edge-ordered.
template <bool STORE16>
__global__ __launch_bounds__(256) void k_edge_gemm(const float* __restrict__ ea,
                                                   const float* __restrict__ escale,
                                                   const float* __restrict__ eshift,
                                                   const bf16* __restrict__ pw16,
                                                   const float* __restrict__ pass_b,
                                                   bf16* __restrict__ attr16,
                                                   float* __restrict__ out1) {
    __shared__ __align__(16) bf16 T[64][136];  // 17408 B
    const int t = threadIdx.x, wave = t >> 6, lane = t & 63, g = lane >> 4, li = lane & 15;
    const int e0 = blockIdx.x * 64;
    const int arow = (wave << 4) + li;
    // A fragments: row = arow, k = ks*32 + g*8 + j
    bf16x8 af[4];
#pragma unroll
    for (int ks = 0; ks < 4; ++ks) {
        const int kb = ks * 32 + g * 8;
        const float* sp = ea + (size_t)(e0 + arow) * PD + kb;
        float4 v0 = *(const float4*)sp;
        float4 v1 = *(const float4*)(sp + 4);
        float4 s0 = *(const float4*)(escale + kb);
        float4 s1 = *(const float4*)(escale + kb + 4);
        float4 f0 = *(const float4*)(eshift + kb);
        float4 f1 = *(const float4*)(eshift + kb + 4);
        bf16x8 pk;
        pk[0] = (bf16)lrelu(fmaf(s0.x, v0.x, f0.x));
        pk[1] = (bf16)lrelu(fmaf(s0.y, v0.y, f0.y));
        pk[2] = (bf16)lrelu(fmaf(s0.z, v0.z, f0.z));
        pk[3] = (bf16)lrelu(fmaf(s0.w, v0.w, f0.w));
        pk[4] = (bf16)lrelu(fmaf(s1.x, v1.x, f1.x));
        pk[5] = (bf16)lrelu(fmaf(s1.y, v1.y, f1.y));
        pk[6] = (bf16)lrelu(fmaf(s1.z, v1.z, f1.z));
        pk[7] = (bf16)lrelu(fmaf(s1.w, v1.w, f1.w));
        af[ks] = pk;
    }
    f32x4 acc[8];
#pragma unroll
    for (int ct = 0; ct < 8; ++ct) acc[ct] = f32x4{0.f, 0.f, 0.f, 0.f};
#pragma unroll
    for (int ks = 0; ks < 4; ++ks) {
        const int kb = ks * 32 + g * 8;
#pragma unroll
        for (int ct = 0; ct < 8; ++ct) {
            const int col = (ct << 4) + li;
            bf16x8 bfr = *(const bf16x8*)(pw16 + col * PD + kb);
            acc[ct] = __builtin_amdgcn_mfma_f32_16x16x32_bf16(af[ks], bfr, acc[ct], 0, 0, 0);
        }
    }
    // bias + convert + LDS transpose
#pragma unroll
    for (int ct = 0; ct < 8; ++ct) {
        const int col = (ct << 4) + li;
        const float pb = pass_b[col];
#pragma unroll
        for (int j = 0; j < 4; ++j) {
            T[(wave << 4) + (g << 2) + j][col] = (bf16)(acc[ct][j] + pb);
        }
    }
    __syncthreads();
    // coalesced stores: 4 threads per row, 64 bf16 each
    {
        const int row = t >> 2, q = t & 3;
        const int e = e0 + row;
        const size_t base = (size_t)e * PD + q * 32;
        const float* eap = ea + base;
        float* o1 = out1 + base;
#pragma unroll
        for (int k = 0; k < 4; ++k) {
            bf16x8 a = *(const bf16x8*)&T[row][q * 32 + k * 8];
            if (STORE16) *(bf16x8*)(attr16 + base + k * 8) = a;
            float4 e0v = *(const float4*)(eap + k * 8);
            float4 e1v = *(const float4*)(eap + k * 8 + 4);
            float4 w0 = {(float)a[0] + e0v.x, (float)a[1] + e0v.y,
                         (float)a[2] + e0v.z, (float)a[3] + e0v.w};
            float4 w1 = {(float)a[4] + e1v.x, (float)a[5] + e1v.y,
                         (float)a[6] + e1v.z, (float)a[7] + e1v.w};
            *(float4*)(o1 + k * 8) = w0;
            *(float4*)(o1 + k * 8 + 4) = w1;
        }
    }
}

// ---------------- aggregation: 256 threads/node, 2 edge-strands + online-softmax merge ----------------
__global__ __launch_bounds__(256) void k_aggregate2(const int* __restrict__ src,
                                                    const int* __restrict__ offs,
                                                    const int* __restrict__ deg,
                                                    const int* __restrict__ perm,
                                                    const bf16* __restrict__ h,
                                                    const bf16* __restrict__ attr16,
                                                    const float* __restrict__ tptr,
                                                    bf16* __restrict__ outpre) {
    __shared__ float shm[128], shd[128], shn[128];
    const int node = blockIdx.x;
    const int t = threadIdx.x;
    const int p = t & 127;
    const int s = t >> 7;  // strand 0/1
    const float tv = tptr[0];
    const int o = offs[node], d = deg[node];
    float m = -3.0e38f, den = 0.f, num = 0.f;
    float aA = 0.f, hA = 0.f, aB = 0.f, hB = 0.f;
    if (s < d) {
        int e = perm[o + s];
        aA = (float)attr16[(size_t)e * PD + p];
        hA = (float)h[(size_t)src[e] * PD + p];
    }
    if (s + 2 < d) {
        int e = perm[o + s + 2];
        aB = (float)attr16[(size_t)e * PD + p];
        hB = (float)h[(size_t)src[e] * PD + p];
    }
    for (int j = s; j < d; j += 2) {
        float av = aA, hv = hA;
        aA = aB; hA = hB;
        if (j + 4 < d) {
            int e = perm[o + j + 4];
            aB = (float)attr16[(size_t)e * PD + p];
            hB = (float)h[(size_t)src[e] * PD + p];
        }
        float msg = hv + av;
        msg = (msg > 0.f ? msg : 0.f) + 1e-7f;
        float sc = msg * tv;
        float nm = fmaxf(m, sc);
        float esc = __expf(m - nm);
        float w = __expf(sc - nm);
        den = den * esc + w;
        num = num * esc + msg * w;
        m = nm;
    }
    if (s == 1) { shm[p] = m; shd[p] = den; shn[p] = num; }
    __syncthreads();
    if (s == 0) {
        float m1 = shm[p], d1 = shd[p], n1 = shn[p];
        float nm = fmaxf(m, m1);
        float agg = 0.f;
        if (d > 0) {
            float e0 = __expf(m - nm), e1 = __expf(m1 - nm);
            float dd = den * e0 + d1 * e1;
            float nn = num * e0 + n1 * e1;
            agg = nn / dd;
        }
        float hv = (float)h[(size_t)node * PD + p];
        outpre[(size_t)node * PD + p] = (bf16)(agg + hv);
    }
}

// fallback (small workspace): recover attr = out1 - ea via perm
__global__ __launch_bounds__(128) void k_aggregateF(const int* __restrict__ src,
                                                    const int* __restrict__ offs,
                                                    const int* __restrict__ deg,
                                                    const int* __restrict__ perm,
                                                    const bf16* __restrict__ h,
                                                    const float* __restrict__ out1,
                                                    const float* __restrict__ ea,
                                                    const float* __restrict__ tptr,
                                                    bf16* __restrict__ outpre) {
    const int node = blockIdx.x;
    const int p = threadIdx.x;
    const float tv = tptr[0];
    const int o = offs[node], d = deg[node];
    float m = -3.0e38f, den = 0.f, num = 0.f;
    for (int j = 0; j < d; ++j) {
        int e = perm[o + j];
        int sI = src[e];
        size_t idx = (size_t)e * PD + p;
        float av = out1[idx] - ea[idx];
        float msg = (float)h[(size_t)sI * PD + p] + av;
        msg = (msg > 0.f ? msg : 0.f) + 1e-7f;
        float sc = msg * tv;
        float nm = fmaxf(m, sc);
        float esc = __expf(m - nm);
        float w = __expf(sc - nm);
        den = den * esc + w;
        num = num * esc + msg * w;
        m = nm;
    }
    float hv = (float)h[(size_t)node * PD + p];
    float agg = (d > 0) ? num / den : 0.f;
    outpre[(size_t)node * PD + p] = (bf16)(agg + hv);
}

// ---------------- MLP: out0 = relu(LN(outpre @ W1^T)) @ W2^T + x ----------------
__global__ __launch_bounds__(256) void k_mlp(const bf16* __restrict__ outpre,
                                             const bf16* __restrict__ w116,
                                             const bf16* __restrict__ w216,
                                             const float* __restrict__ lng,
                                             const float* __restrict__ lnb,
                                             const float* __restrict__ x,
                                             float* __restrict__ out0) {
    __shared__ __align__(16) float SM[64][132];  // aliased as A2 (64x256 bf16)
    bf16* A2 = (bf16*)&SM[0][0];
    const int t = threadIdx.x, wave = t >> 6, lane = t & 63, g = lane >> 4, li = lane & 15;
    const size_t n0 = (size_t)blockIdx.x * 64;
    const int arow = (wave << 4) + li;
    f32x4 accY[16];
#pragma unroll
    for (int ct = 0; ct < 16; ++ct) accY[ct] = f32x4{0.f, 0.f, 0.f, 0.f};
#pragma unroll
    for (int ks = 0; ks < 4; ++ks) {
        int kb = ks * 32 + g * 8;
        bf16x8 af = *(const bf16x8*)(outpre + (n0 + arow) * PD + kb);
#pragma unroll
        for (int ct = 0; ct < 16; ++ct) {
            int col = (ct << 4) + li;
            bf16x8 bfr = *(const bf16x8*)(w116 + col * PD + kb);
            accY[ct] = __builtin_amdgcn_mfma_f32_16x16x32_bf16(af, bfr, accY[ct], 0, 0, 0);
        }
    }
#pragma unroll
    for (int j = 0; j < 4; ++j) {
        float s1 = 0.f, s2 = 0.f;
#pragma unroll
        for (int ct = 0; ct < 16; ++ct) {
            float v = accY[ct][j];
            s1 += v; s2 += v * v;
        }
        for (int o = 1; o < 16; o <<= 1) {
            s1 += __shfl_xor(s1, o);
            s2 += __shfl_xor(s2, o);
        }
        float mean = s1 * (1.f / HD);
        float var = s2 * (1.f / HD) - mean * mean;
        float rstd = rsqrtf(var + 1e-5f);
        int row = (wave << 4) + (g << 2) + j;
#pragma unroll
        for (int ct = 0; ct < 16; ++ct) {
            int col = (ct << 4) + li;
            float v = (accY[ct][j] - mean) * rstd;
            v = lng[col] * v + lnb[col];
            v = v > 0.f ? v : 0.f;
            A2[(row << 8) + (col ^ ((row & 7) << 3))] = (bf16)v;
        }
    }
    __syncthreads();
    f32x4 accZ[8];
#pragma unroll
    for (int ct = 0; ct < 8; ++ct) accZ[ct] = f32x4{0.f, 0.f, 0.f, 0.f};
#pragma unroll
    for (int ks = 0; ks < 8; ++ks) {
        int kb = ks * 32 + g * 8;
        bf16x8 af = *(const bf16x8*)&A2[(arow << 8) + (kb ^ ((arow & 7) << 3))];
#pragma unroll
        for (int ct = 0; ct < 8; ++ct) {
            int col = (ct << 4) + li;
            bf16x8 bfr = *(const bf16x8*)(w216 + col * HD + kb);
            accZ[ct] = __builtin_amdgcn_mfma_f32_16x16x32_bf16(af, bfr, accZ[ct], 0, 0, 0);
        }
    }
    __syncthreads();  // done reading A2
#pragma unroll
    for (int ct = 0; ct < 8; ++ct) {
        int col = (ct << 4) + li;
#pragma unroll
        for (int j = 0; j < 4; ++j) {
            int row = (wave << 4) + (g << 2) + j;
            SM[row][col] = accZ[ct][j];
        }
    }
    __syncthreads();
    {
        const int row = t >> 2, q = t & 3;
        const size_t n = n0 + row;
        if (n < NN) {
            const size_t base = n * PD + q * 32;
            const float* rp = &SM[row][q * 32];
            const float* xp = x + base;
            float* op = out0 + base;
#pragma unroll
            for (int k = 0; k < 8; ++k) {
                float4 r = *(const float4*)(rp + k * 4);
                float4 xv = *(const float4*)(xp + k * 4);
                float4 w = {r.x + xv.x, r.y + xv.y, r.z + xv.z, r.w + xv.w};
                *(float4*)(op + k * 4) = w;
            }
        }
    }
}

extern "C" void kernel_launch(void* const* d_in, const int* in_sizes, int n_in,
                              void* d_out, int out_size, void* d_ws, size_t ws_size,
                              hipStream_t stream) {
    const float* x = (const float*)d_in[0];
    const int* ei = (const int*)d_in[1];
    const float* ea = (const float*)d_in[2];
    const int* batch = (const int*)d_in[3];
    const float* gnw = (const float*)d_in[4];
    const float* gnb = (const float*)d_in[5];
    const float* gms = (const float*)d_in[6];
    const float* bng = (const float*)d_in[7];
    const float* bnb = (const float*)d_in[8];
    const float* pW = (const float*)d_in[9];
    const float* pb = (const float*)d_in[10];
    const float* tp = (const float*)d_in[11];
    const float* W1 = (const float*)d_in[12];
    const float* lng = (const float*)d_in[13];
    const float* lnb = (const float*)d_in[14];
    const float* W2 = (const float*)d_in[15];
    const int* srcI = ei;
    const int* dstI = ei + NE;
    float* out0 = (float*)d_out;
    float* out1 = out0 + (size_t)NN * PD;

    char* w = (char*)d_ws;
    size_t off = 0;
    auto alloc = [&](size_t bytes) -> char* {
        char* p = w + off;
        off += (bytes + 255) & ~(size_t)255;
        return p;
    };
    float* gsum = (float*)alloc(NG * PD * 4);
    float* gsq = (float*)alloc(NG * PD * 4);
    float* colsum = (float*)alloc(PD * 4);
    float* colsq = (float*)alloc(PD * 4);
    int* gcnt = (int*)alloc(NG * 4);
    int* deg = (int*)alloc(NN * 4);
    int* cursor = (int*)alloc(NN * 4);
    size_t zero_bytes = off;  // everything above must be zeroed each call
    int* offs = (int*)alloc(NN * 4);
    int* perm = (int*)alloc((size_t)NE * 4);
    int* part = (int*)alloc(NPART * 4);
    int* ptot = (int*)alloc(NPART * 4);
    float* gA = (float*)alloc(NG * PD * 4);
    float* gB = (float*)alloc(NG * PD * 4);
    float* escale = (float*)alloc(PD * 4);
    float* eshift = (float*)alloc(PD * 4);
    bf16* pw16 = (bf16*)alloc(PD * PD * 2);
    bf16* w116 = (bf16*)alloc(HD * PD * 2);
    bf16* w216 = (bf16*)alloc(PD * HD * 2);
    bf16* h16 = (bf16*)alloc((size_t)NN * PD * 2);
    bf16* outpre = (bf16*)alloc((size_t)NPAD * PD * 2);
    size_t small_total = off;
    bf16* attr16 = (bf16*)alloc((size_t)NE * PD * 2);
    size_t big_total = off;
    if (ws_size < small_total) return;  // cannot run
    const bool big = (ws_size >= big_total);

    hipMemsetAsync(d_ws, 0, zero_bytes, stream);
    k_convert_weights<<<128, 256, 0, stream>>>(pW, W1, W2, pw16, w116, w216);
    k_gn_stats<<<(NN + 63) / 64, 128, 0, stream>>>(x, batch, gsum, gsq, gcnt);
    k_gn_finalize<<<(NG * PD + 255) / 256, 256, 0, stream>>>(gsum, gsq, gcnt, gnw, gnb, gms, gA, gB);
    k_compute_h<<<(NN * PD + 255) / 256, 256, 0, stream>>>(x, batch, gA, gB, h16);
    k_bn_stats<<<(NE + 511) / 512, 256, 0, stream>>>(ea, colsum, colsq);
    k_bn_finalize<<<1, 128, 0, stream>>>(colsum, colsq, bng, bnb, escale, eshift);
    k_deg<<<(NE + 255) / 256, 256, 0, stream>>>(dstI, deg);
    k_scan_part<<<NPART, 256, 0, stream>>>(deg, part);
    k_scan_tops<<<1, 64, 0, stream>>>(part, ptot);
    k_scan_final<<<NPART, 256, 0, stream>>>(deg, ptot, offs);
    k_scatter<<<(NE + 255) / 256, 256, 0, stream>>>(dstI, offs, cursor, perm);
    if (big) {
        k_edge_gemm<true><<<NE / 64, 256, 0, stream>>>(ea, escale, eshift, pw16, pb, attr16, out1);
        k_aggregate2<<<NN, 256, 0, stream>>>(srcI, offs, deg, perm, h16, attr16, tp, outpre);
    } else {
        k_edge_gemm<false><<<NE / 64, 256, 0, stream>>>(ea, escale, eshift, pw16, pb, nullptr, out1);
        k_aggregateF<<<NN, 128, 0, stream>>>(srcI, offs, deg, perm, h16, out1, ea, tp, outpre);
    }
    k_mlp<<<NPAD / 64, 256, 0, stream>>>(outpre, w116, w216, lng, lnb, x, out0);
}

// Round 5
// 766.352 us; speedup vs baseline: 1.2954x; 1.2954x over previous
//
#include <hip/hip_runtime.h>
#include <hip/hip_bf16.h>

#define NN 50000
#define NE 600000
#define NG 64
#define PD 128
#define HD 256
#define NPAD 50048   // ceil(NN/64)*64
#define NPART 49     // ceil(NN/1024)

typedef __bf16 bf16;
typedef __bf16 bf16x8 __attribute__((ext_vector_type(8)));
typedef __bf16 bf16x4 __attribute__((ext_vector_type(4)));
typedef float f32x4 __attribute__((ext_vector_type(4)));

__device__ __forceinline__ float lrelu(float x) { return x > 0.f ? x : 0.01f * x; }

// ---------------- weights -> bf16 ----------------
__global__ void k_convert_weights(const float* __restrict__ pw, const float* __restrict__ w1,
                                  const float* __restrict__ w2, bf16* __restrict__ pw16,
                                  bf16* __restrict__ w116, bf16* __restrict__ w216) {
    int i = blockIdx.x * 256 + threadIdx.x;
    if (i < PD * PD) pw16[i] = (bf16)pw[i];
    if (i < HD * PD) w116[i] = (bf16)w1[i];
    if (i < PD * HD) w216[i] = (bf16)w2[i];
}

// ---------------- GraphNorm stats (batch is sorted) ----------------
__global__ __launch_bounds__(128) void k_gn_stats(const float* __restrict__ x,
                                                  const int* __restrict__ batch,
                                                  float* __restrict__ gsum, float* __restrict__ gsq,
                                                  int* __restrict__ gcnt) {
    int p = threadIdx.x;  // 128
    int base = blockIdx.x * 64;
    int end = min(base + 64, NN);
    float s = 0.f, q = 0.f;
    int cur = batch[base];
    int runstart = base;
    for (int i = base; i < end; ++i) {
        int g = batch[i];
        if (g != cur) {
            atomicAdd(&gsum[cur * PD + p], s);
            atomicAdd(&gsq[cur * PD + p], q);
            if (p == 0) atomicAdd(&gcnt[cur], i - runstart);
            s = 0.f; q = 0.f; cur = g; runstart = i;
        }
        float v = x[(size_t)i * PD + p];
        s += v; q += v * v;
    }
    atomicAdd(&gsum[cur * PD + p], s);
    atomicAdd(&gsq[cur * PD + p], q);
    if (p == 0) atomicAdd(&gcnt[cur], end - runstart);
}

__global__ void k_gn_finalize(const float* __restrict__ gsum, const float* __restrict__ gsq,
                              const int* __restrict__ gcnt, const float* __restrict__ gw,
                              const float* __restrict__ gb, const float* __restrict__ gms,
                              float* __restrict__ gA, float* __restrict__ gB) {
    int i = blockIdx.x * 256 + threadIdx.x;
    if (i >= NG * PD) return;
    int p = i & (PD - 1);
    float c = (float)max(gcnt[i >> 7], 1);
    float m = gsum[i] / c;
    float q = gsq[i] / c;
    float s = gms[p];
    float var = q - m * m * (2.f * s - s * s);
    float inv = rsqrtf(var + 1e-5f);
    float a = gw[p] * inv;
    gA[i] = a;
    gB[i] = gb[p] - a * s * m;
}

// vectorized: each thread handles 8 elements
__global__ __launch_bounds__(256) void k_compute_h(const float* __restrict__ x,
                                                   const int* __restrict__ batch,
                                                   const float* __restrict__ gA,
                                                   const float* __restrict__ gB,
                                                   bf16* __restrict__ h) {
    int i = blockIdx.x * 256 + threadIdx.x;  // over NN*PD/8
    if (i >= NN * PD / 8) return;
    int node = i >> 4;
    int cb = (i & 15) * 8;
    int g = batch[node];
    const float* xp = x + (size_t)node * PD + cb;
    float4 v0 = *(const float4*)xp;
    float4 v1 = *(const float4*)(xp + 4);
    const float* ap = gA + g * PD + cb;
    const float* bp = gB + g * PD + cb;
    float4 a0 = *(const float4*)ap, a1 = *(const float4*)(ap + 4);
    float4 b0 = *(const float4*)bp, b1 = *(const float4*)(bp + 4);
    bf16x8 pk;
    pk[0] = (bf16)lrelu(fmaf(a0.x, v0.x, b0.x));
    pk[1] = (bf16)lrelu(fmaf(a0.y, v0.y, b0.y));
    pk[2] = (bf16)lrelu(fmaf(a0.z, v0.z, b0.z));
    pk[3] = (bf16)lrelu(fmaf(a0.w, v0.w, b0.w));
    pk[4] = (bf16)lrelu(fmaf(a1.x, v1.x, b1.x));
    pk[5] = (bf16)lrelu(fmaf(a1.y, v1.y, b1.y));
    pk[6] = (bf16)lrelu(fmaf(a1.z, v1.z, b1.z));
    pk[7] = (bf16)lrelu(fmaf(a1.w, v1.w, b1.w));
    *(bf16x8*)(h + (size_t)i * 8) = pk;
}

// ---------------- edge BN stats (float4 loads) ----------------
__global__ __launch_bounds__(256) void k_bn_stats(const float* __restrict__ ea,
                                                  float* __restrict__ colsum,
                                                  float* __restrict__ colsq) {
    const int t = threadIdx.x;
    const int cq = (t & 31) * 4;
    const int ro = t >> 5;
    const size_t base = (size_t)blockIdx.x * 512;
    f32x4 s = {0.f, 0.f, 0.f, 0.f}, q = {0.f, 0.f, 0.f, 0.f};
    for (int r = 0; r < 64; ++r) {
        size_t e = base + (size_t)r * 8 + ro;
        if (e < NE) {
            float4 v = *(const float4*)(ea + e * PD + cq);
            s[0] += v.x; s[1] += v.y; s[2] += v.z; s[3] += v.w;
            q[0] += v.x * v.x; q[1] += v.y * v.y; q[2] += v.z * v.z; q[3] += v.w * v.w;
        }
    }
    __shared__ f32x4 shA[256], shB[256];
    shA[t] = s; shB[t] = q;
    __syncthreads();
    if (t < 128) { shA[t] += shA[t + 128]; shB[t] += shB[t + 128]; }
    __syncthreads();
    if (t < 64) { shA[t] += shA[t + 64]; shB[t] += shB[t + 64]; }
    __syncthreads();
    if (t < 32) {
        f32x4 a = shA[t] + shA[t + 32];
        f32x4 b = shB[t] + shB[t + 32];
#pragma unroll
        for (int i = 0; i < 4; ++i) {
            atomicAdd(&colsum[t * 4 + i], a[i]);
            atomicAdd(&colsq[t * 4 + i], b[i]);
        }
    }
}

__global__ void k_bn_finalize(const float* __restrict__ colsum, const float* __restrict__ colsq,
                              const float* __restrict__ gamma, const float* __restrict__ beta,
                              float* __restrict__ escale, float* __restrict__ eshift) {
    int p = threadIdx.x;
    float m = colsum[p] / (float)NE;
    float v = colsq[p] / (float)NE - m * m;
    float sc = gamma[p] * rsqrtf(v + 1e-5f);
    escale[p] = sc;
    eshift[p] = beta[p] - sc * m;
}

// ---------------- CSR by dst ----------------
__global__ void k_deg(const int* __restrict__ dst, int* __restrict__ deg) {
    int e = blockIdx.x * 256 + threadIdx.x;
    if (e < NE) atomicAdd(&deg[dst[e]], 1);
}

__global__ __launch_bounds__(256) void k_scan_part(const int* __restrict__ deg,
                                                   int* __restrict__ part) {
    __shared__ int sh[256];
    int b = blockIdx.x, t = threadIdx.x;
    int base = b * 1024;
    int s = 0;
#pragma unroll
    for (int k = 0; k < 4; ++k) {
        int i = base + k * 256 + t;
        if (i < NN) s += deg[i];
    }
    sh[t] = s;
    __syncthreads();
    for (int st = 128; st > 0; st >>= 1) {
        if (t < st) sh[t] += sh[t + st];
        __syncthreads();
    }
    if (t == 0) part[b] = sh[0];
}

__global__ void k_scan_tops(const int* __restrict__ part, int* __restrict__ ptot) {
    int t = threadIdx.x;  // 64
    int v = (t < NPART) ? part[t] : 0;
    int orig = v;
    for (int s = 1; s < 64; s <<= 1) {
        int u = __shfl_up(v, s);
        if (t >= s) v += u;
    }
    if (t < NPART) ptot[t] = v - orig;  // exclusive
}

__global__ __launch_bounds__(256) void k_scan_final(const int* __restrict__ deg,
                                                    const int* __restrict__ ptot,
                                                    int* __restrict__ offs) {
    __shared__ int sh[256];
    int b = blockIdx.x, t = threadIdx.x;
    int i0 = b * 1024 + t * 4;
    int v0 = (i0 + 0 < NN) ? deg[i0 + 0] : 0;
    int v1 = (i0 + 1 < NN) ? deg[i0 + 1] : 0;
    int v2 = (i0 + 2 < NN) ? deg[i0 + 2] : 0;
    int v3 = (i0 + 3 < NN) ? deg[i0 + 3] : 0;
    int s = v0 + v1 + v2 + v3;
    sh[t] = s;
    __syncthreads();
    for (int st = 1; st < 256; st <<= 1) {
        int add = (t >= st) ? sh[t - st] : 0;
        __syncthreads();
        sh[t] += add;
        __syncthreads();
    }
    int pre = sh[t] - s + ptot[b];
    if (i0 + 0 < NN) offs[i0 + 0] = pre;
    if (i0 + 1 < NN) offs[i0 + 1] = pre + v0;
    if (i0 + 2 < NN) offs[i0 + 2] = pre + v0 + v1;
    if (i0 + 3 < NN) offs[i0 + 3] = pre + v0 + v1 + v2;
}

__global__ void k_scatter(const int* __restrict__ src, const int* __restrict__ dst,
                          const int* __restrict__ offs, int* __restrict__ cursor,
                          int* __restrict__ perm, int* __restrict__ srcP) {
    int e = blockIdx.x * 256 + threadIdx.x;
    if (e < NE) {
        int d = dst[e];
        int pos = atomicAdd(&cursor[d], 1);
        int r = offs[d] + pos;
        perm[r] = e;
        srcP[r] = src[e];
    }
}

// ---------------- edge norm + GEMM: attr = leaky(bn(ea)) @ W^T + b ----------------
// Direct-global A-fragments; single barrier; flat bf16 LDS tile; FLAT wave-contiguous epilogue:
// instruction i, thread t handles element i*1024 + t*4 (out1) / i*2048 + t*8 (attr16).
template <bool STORE16>
__global__ __launch_bounds__(256) void k_edge_gemm(const float* __restrict__ ea,
                                                   const float* __restrict__ escale,
                                                   const float* __restrict__ eshift,
                                                   const bf16* __restrict__ pw16,
                                                   const float* __restrict__ pass_b,
                                                   bf16* __restrict__ attr16,
                                                   float* __restrict__ out1) {
    __shared__ __align__(16) bf16 T[64 * PD];  // 16384 B flat
    const int t = threadIdx.x, wave = t >> 6, lane = t & 63, g = lane >> 4, li = lane & 15;
    const int e0 = blockIdx.x * 64;
    const int arow = (wave << 4) + li;
    // A fragments: row = arow, k = ks*32 + g*8 + j
    bf16x8 af[4];
#pragma unroll
    for (int ks = 0; ks < 4; ++ks) {
        const int kb = ks * 32 + g * 8;
        const float* sp = ea + (size_t)(e0 + arow) * PD + kb;
        float4 v0 = *(const float4*)sp;
        float4 v1 = *(const float4*)(sp + 4);
        float4 s0 = *(const float4*)(escale + kb);
        float4 s1 = *(const float4*)(escale + kb + 4);
        float4 f0 = *(const float4*)(eshift + kb);
        float4 f1 = *(const float4*)(eshift + kb + 4);
        bf16x8 pk;
        pk[0] = (bf16)lrelu(fmaf(s0.x, v0.x, f0.x));
        pk[1] = (bf16)lrelu(fmaf(s0.y, v0.y, f0.y));
        pk[2] = (bf16)lrelu(fmaf(s0.z, v0.z, f0.z));
        pk[3] = (bf16)lrelu(fmaf(s0.w, v0.w, f0.w));
        pk[4] = (bf16)lrelu(fmaf(s1.x, v1.x, f1.x));
        pk[5] = (bf16)lrelu(fmaf(s1.y, v1.y, f1.y));
        pk[6] = (bf16)lrelu(fmaf(s1.z, v1.z, f1.z));
        pk[7] = (bf16)lrelu(fmaf(s1.w, v1.w, f1.w));
        af[ks] = pk;
    }
    f32x4 acc[8];
#pragma unroll
    for (int ct = 0; ct < 8; ++ct) acc[ct] = f32x4{0.f, 0.f, 0.f, 0.f};
#pragma unroll
    for (int ks = 0; ks < 4; ++ks) {
        const int kb = ks * 32 + g * 8;
#pragma unroll
        for (int ct = 0; ct < 8; ++ct) {
            const int col = (ct << 4) + li;
            bf16x8 bfr = *(const bf16x8*)(pw16 + col * PD + kb);
            acc[ct] = __builtin_amdgcn_mfma_f32_16x16x32_bf16(af[ks], bfr, acc[ct], 0, 0, 0);
        }
    }
    // bias + convert + flat LDS scatter (MFMA C layout)
#pragma unroll
    for (int ct = 0; ct < 8; ++ct) {
        const int col = (ct << 4) + li;
        const float pb = pass_b[col];
#pragma unroll
        for (int j = 0; j < 4; ++j) {
            const int row = (wave << 4) + (g << 2) + j;
            T[(row << 7) + col] = (bf16)(acc[ct][j] + pb);
        }
    }
    __syncthreads();
    const size_t gbase = (size_t)e0 * PD;
    if (STORE16) {
#pragma unroll
        for (int i = 0; i < 4; ++i) {
            const int idx = i * 2048 + t * 8;
            *(bf16x8*)(attr16 + gbase + idx) = *(const bf16x8*)&T[idx];
        }
    }
#pragma unroll
    for (int i = 0; i < 8; ++i) {
        const int idx = i * 1024 + t * 4;
        bf16x4 a = *(const bf16x4*)&T[idx];
        float4 e0v = *(const float4*)(ea + gbase + idx);
        float4 w = {(float)a[0] + e0v.x, (float)a[1] + e0v.y,
                    (float)a[2] + e0v.z, (float)a[3] + e0v.w};
        *(float4*)(out1 + gbase + idx) = w;
    }
}

// ---------------- per-node online-softmax aggregation + residual (depth-2 pipelined) ----------------
__global__ __launch_bounds__(128) void k_aggregate(const int* __restrict__ srcP,
                                                   const int* __restrict__ offs,
                                                   const int* __restrict__ deg,
                                                   const int* __restrict__ perm,
                                                   const bf16* __restrict__ h,
                                                   const bf16* __restrict__ attr16,
                                                   const float* __restrict__ tptr,
                                                   bf16* __restrict__ outpre) {
    const int node = blockIdx.x;
    const int p = threadIdx.x;
    const float tv = tptr[0];
    const int o = offs[node], d = deg[node];
    float m = -3.0e38f, den = 0.f, num = 0.f;
    float aA = 0.f, hA = 0.f, aB = 0.f, hB = 0.f;
    if (d > 0) {
        aA = (float)attr16[(size_t)perm[o] * PD + p];
        hA = (float)h[(size_t)srcP[o] * PD + p];
    }
    if (d > 1) {
        aB = (float)attr16[(size_t)perm[o + 1] * PD + p];
        hB = (float)h[(size_t)srcP[o + 1] * PD + p];
    }
    for (int j = 0; j < d; ++j) {
        float av = aA, hv = hA;
        aA = aB; hA = hB;
        if (j + 2 < d) {
            aB = (float)attr16[(size_t)perm[o + j + 2] * PD + p];
            hB = (float)h[(size_t)srcP[o + j + 2] * PD + p];
        }
        float msg = hv + av;
        msg = (msg > 0.f ? msg : 0.f) + 1e-7f;
        float sc = msg * tv;
        float nm = fmaxf(m, sc);
        float esc = __expf(m - nm);
        float w = __expf(sc - nm);
        den = den * esc + w;
        num = num * esc + msg * w;
        m = nm;
    }
    float hv = (float)h[(size_t)node * PD + p];
    float agg = (d > 0) ? num / den : 0.f;
    outpre[(size_t)node * PD + p] = (bf16)(agg + hv);
}

// fallback (small workspace): recover attr = out1 - ea via perm
__global__ __launch_bounds__(128) void k_aggregateF(const int* __restrict__ srcP,
                                                    const int* __restrict__ offs,
                                                    const int* __restrict__ deg,
                                                    const int* __restrict__ perm,
                                                    const bf16* __restrict__ h,
                                                    const float* __restrict__ out1,
                                                    const float* __restrict__ ea,
                                                    const float* __restrict__ tptr,
                                                    bf16* __restrict__ outpre) {
    const int node = blockIdx.x;
    const int p = threadIdx.x;
    const float tv = tptr[0];
    const int o = offs[node], d = deg[node];
    float m = -3.0e38f, den = 0.f, num = 0.f;
    for (int j = 0; j < d; ++j) {
        int e = perm[o + j];
        int sI = srcP[o + j];
        size_t idx = (size_t)e * PD + p;
        float av = out1[idx] - ea[idx];
        float msg = (float)h[(size_t)sI * PD + p] + av;
        msg = (msg > 0.f ? msg : 0.f) + 1e-7f;
        float sc = msg * tv;
        float nm = fmaxf(m, sc);
        float esc = __expf(m - nm);
        float w = __expf(sc - nm);
        den = den * esc + w;
        num = num * esc + msg * w;
        m = nm;
    }
    float hv = (float)h[(size_t)node * PD + p];
    float agg = (d > 0) ? num / den : 0.f;
    outpre[(size_t)node * PD + p] = (bf16)(agg + hv);
}

// ---------------- MLP: out0 = relu(LN(outpre @ W1^T)) @ W2^T + x ----------------
__global__ __launch_bounds__(256) void k_mlp(const bf16* __restrict__ outpre,
                                             const bf16* __restrict__ w116,
                                             const bf16* __restrict__ w216,
                                             const float* __restrict__ lng,
                                             const float* __restrict__ lnb,
                                             const float* __restrict__ x,
                                             float* __restrict__ out0) {
    __shared__ __align__(16) float SM[64][132];  // aliased as A2 (64x256 bf16)
    bf16* A2 = (bf16*)&SM[0][0];
    const int t = threadIdx.x, wave = t >> 6, lane = t & 63, g = lane >> 4, li = lane & 15;
    const size_t n0 = (size_t)blockIdx.x * 64;
    const int arow = (wave << 4) + li;
    f32x4 accY[16];
#pragma unroll
    for (int ct = 0; ct < 16; ++ct) accY[ct] = f32x4{0.f, 0.f, 0.f, 0.f};
#pragma unroll
    for (int ks = 0; ks < 4; ++ks) {
        int kb = ks * 32 + g * 8;
        bf16x8 af = *(const bf16x8*)(outpre + (n0 + arow) * PD + kb);
#pragma unroll
        for (int ct = 0; ct < 16; ++ct) {
            int col = (ct << 4) + li;
            bf16x8 bfr = *(const bf16x8*)(w116 + col * PD + kb);
            accY[ct] = __builtin_amdgcn_mfma_f32_16x16x32_bf16(af, bfr, accY[ct], 0, 0, 0);
        }
    }
#pragma unroll
    for (int j = 0; j < 4; ++j) {
        float s1 = 0.f, s2 = 0.f;
#pragma unroll
        for (int ct = 0; ct < 16; ++ct) {
            float v = accY[ct][j];
            s1 += v; s2 += v * v;
        }
        for (int o = 1; o < 16; o <<= 1) {
            s1 += __shfl_xor(s1, o);
            s2 += __shfl_xor(s2, o);
        }
        float mean = s1 * (1.f / HD);
        float var = s2 * (1.f / HD) - mean * mean;
        float rstd = rsqrtf(var + 1e-5f);
        int row = (wave << 4) + (g << 2) + j;
#pragma unroll
        for (int ct = 0; ct < 16; ++ct) {
            int col = (ct << 4) + li;
            float v = (accY[ct][j] - mean) * rstd;
            v = lng[col] * v + lnb[col];
            v = v > 0.f ? v : 0.f;
            A2[(row << 8) + (col ^ ((row & 7) << 3))] = (bf16)v;
        }
    }
    __syncthreads();
    f32x4 accZ[8];
#pragma unroll
    for (int ct = 0; ct < 8; ++ct) accZ[ct] = f32x4{0.f, 0.f, 0.f, 0.f};
#pragma unroll
    for (int ks = 0; ks < 8; ++ks) {
        int kb = ks * 32 + g * 8;
        bf16x8 af = *(const bf16x8*)&A2[(arow << 8) + (kb ^ ((arow & 7) << 3))];
#pragma unroll
        for (int ct = 0; ct < 8; ++ct) {
            int col = (ct << 4) + li;
            bf16x8 bfr = *(const bf16x8*)(w216 + col * HD + kb);
            accZ[ct] = __builtin_amdgcn_mfma_f32_16x16x32_bf16(af, bfr, accZ[ct], 0, 0, 0);
        }
    }
    __syncthreads();  // done reading A2
#pragma unroll
    for (int ct = 0; ct < 8; ++ct) {
        int col = (ct << 4) + li;
#pragma unroll
        for (int j = 0; j < 4; ++j) {
            int row = (wave << 4) + (g << 2) + j;
            SM[row][col] = accZ[ct][j];
        }
    }
    __syncthreads();
    // flat wave-contiguous stores (rows are 128 f32; pad only affects LDS addressing)
    {
        const size_t gb = n0 * PD;
#pragma unroll
        for (int i = 0; i < 8; ++i) {
            const int idx = i * 1024 + t * 4;
            const int row = idx >> 7, col = idx & 127;
            const size_t n = n0 + row;
            if (n < NN) {
                float4 r = *(const float4*)&SM[row][col];
                float4 xv = *(const float4*)(x + gb + idx);
                float4 w = {r.x + xv.x, r.y + xv.y, r.z + xv.z, r.w + xv.w};
                *(float4*)(out0 + gb + idx) = w;
            }
        }
    }
}

extern "C" void kernel_launch(void* const* d_in, const int* in_sizes, int n_in,
                              void* d_out, int out_size, void* d_ws, size_t ws_size,
                              hipStream_t stream) {
    const float* x = (const float*)d_in[0];
    const int* ei = (const int*)d_in[1];
    const float* ea = (const float*)d_in[2];
    const int* batch = (const int*)d_in[3];
    const float* gnw = (const float*)d_in[4];
    const float* gnb = (const float*)d_in[5];
    const float* gms = (const float*)d_in[6];
    const float* bng = (const float*)d_in[7];
    const float* bnb = (const float*)d_in[8];
    const float* pW = (const float*)d_in[9];
    const float* pb = (const float*)d_in[10];
    const float* tp = (const float*)d_in[11];
    const float* W1 = (const float*)d_in[12];
    const float* lng = (const float*)d_in[13];
    const float* lnb = (const float*)d_in[14];
    const float* W2 = (const float*)d_in[15];
    const int* srcI = ei;
    const int* dstI = ei + NE;
    float* out0 = (float*)d_out;
    float* out1 = out0 + (size_t)NN * PD;

    char* w = (char*)d_ws;
    size_t off = 0;
    auto alloc = [&](size_t bytes) -> char* {
        char* p = w + off;
        off += (bytes + 255) & ~(size_t)255;
        return p;
    };
    float* gsum = (float*)alloc(NG * PD * 4);
    float* gsq = (float*)alloc(NG * PD * 4);
    float* colsum = (float*)alloc(PD * 4);
    float* colsq = (float*)alloc(PD * 4);
    int* gcnt = (int*)alloc(NG * 4);
    int* deg = (int*)alloc(NN * 4);
    int* cursor = (int*)alloc(NN * 4);
    size_t zero_bytes = off;  // everything above must be zeroed each call
    int* offs = (int*)alloc(NN * 4);
    int* perm = (int*)alloc((size_t)NE * 4);
    int* srcP = (int*)alloc((size_t)NE * 4);
    int* part = (int*)alloc(NPART * 4);
    int* ptot = (int*)alloc(NPART * 4);
    float* gA = (float*)alloc(NG * PD * 4);
    float* gB = (float*)alloc(NG * PD * 4);
    float* escale = (float*)alloc(PD * 4);
    float* eshift = (float*)alloc(PD * 4);
    bf16* pw16 = (bf16*)alloc(PD * PD * 2);
    bf16* w116 = (bf16*)alloc(HD * PD * 2);
    bf16* w216 = (bf16*)alloc(PD * HD * 2);
    bf16* h16 = (bf16*)alloc((size_t)NN * PD * 2);
    bf16* outpre = (bf16*)alloc((size_t)NPAD * PD * 2);
    size_t small_total = off;
    bf16* attr16 = (bf16*)alloc((size_t)NE * PD * 2);
    size_t big_total = off;
    if (ws_size < small_total) return;  // cannot run
    const bool big = (ws_size >= big_total);

    hipMemsetAsync(d_ws, 0, zero_bytes, stream);
    k_convert_weights<<<128, 256, 0, stream>>>(pW, W1, W2, pw16, w116, w216);
    k_gn_stats<<<(NN + 63) / 64, 128, 0, stream>>>(x, batch, gsum, gsq, gcnt);
    k_gn_finalize<<<(NG * PD + 255) / 256, 256, 0, stream>>>(gsum, gsq, gcnt, gnw, gnb, gms, gA, gB);
    k_compute_h<<<(NN * PD / 8 + 255) / 256, 256, 0, stream>>>(x, batch, gA, gB, h16);
    k_bn_stats<<<(NE + 511) / 512, 256, 0, stream>>>(ea, colsum, colsq);
    k_bn_finalize<<<1, 128, 0, stream>>>(colsum, colsq, bng, bnb, escale, eshift);
    k_deg<<<(NE + 255) / 256, 256, 0, stream>>>(dstI, deg);
    k_scan_part<<<NPART, 256, 0, stream>>>(deg, part);
    k_scan_tops<<<1, 64, 0, stream>>>(part, ptot);
    k_scan_final<<<NPART, 256, 0, stream>>>(deg, ptot, offs);
    k_scatter<<<(NE + 255) / 256, 256, 0, stream>>>(srcI, dstI, offs, cursor, perm, srcP);
    if (big) {
        k_edge_gemm<true><<<NE / 64, 256, 0, stream>>>(ea, escale, eshift, pw16, pb, attr16, out1);
        k_aggregate<<<NN, 128, 0, stream>>>(srcP, offs, deg, perm, h16, attr16, tp, outpre);
    } else {
        k_edge_gemm<false><<<NE / 64, 256, 0, stream>>>(ea, escale, eshift, pw16, pb, nullptr, out1);
        k_aggregateF<<<NN, 128, 0, stream>>>(srcP, offs, deg, perm, h16, out1, ea, tp, outpre);
    }
    k_mlp<<<NPAD / 64, 256, 0, stream>>>(outpre, w116, w216, lng, lnb, x, out0);
}